// Round 8
// baseline (276.603 us; speedup 1.0000x reference)
//
#include <hip/hip_runtime.h>
#include <math.h>

typedef __attribute__((ext_vector_type(8))) short short8;
typedef __attribute__((ext_vector_type(4))) float float4v;
typedef __attribute__((ext_vector_type(2))) float float2v;

struct P {
  const float *t_clip, *v_clip, *sbert;
  const float *Wt, *bt, *Wv, *bv, *Wc, *bc;
  const float *Wp1, *bp1, *Wp2, *bp2, *Wm1, *bm1, *Wm2, *bm2;
  const float *tau_logits, *U, *V, *Wg1, *bg1, *Wg2, *bg2, *w_out, *b_out, *concept_q;
  const int *pid;
  // bf16 tile buffers (A-tile: idx=(row>>4)*K16+(k>>5)*512+((k>>3)&3)*128+(row&15)*8+(k&7); B-tile same with row->n)
  unsigned short *tvbf;             // A M=128 K=768, x2 (sel: 0=v,1=t)
  unsigned short *sbbf;             // A M=1024 K=384
  unsigned short *wtvB;             // B K=768 N=256, x2 (sel)
  unsigned short *wcB;              // B K=384 N=256
  unsigned short *wg1B;             // B K=384 N=64
  unsigned short *wg2B;             // B K=64 N=64
  unsigned short *w2bf;             // A M=512 K=256, x2 (mat)
  unsigned short *uvB;              // B K=256 N=128 ([U|V])
  unsigned short *w1upP, *w1upM;    // B K=512 N=512
  unsigned short *w1lowP, *w1lowM;  // B K=256 N=512
  unsigned short *vtbf;             // A M=128 K=512
  unsigned short *dbf;              // A M=1024 K=256
  unsigned short *ghbf;             // A M=1024 K=64
  unsigned short *Ctp, *Ctm;        // acts addend, tiled: byte = kt*16384 + n*1024 + quad*256 + m*16
  unsigned short *Wpk, *Wmk;        // W-tile: (j>>5)*4096+(c>>4)*512+((j>>3)&3)*128+(c&15)*8+(j&7)
  float *Ap, *Am;
  float *sBuf, *biasPM, *tau, *gw, *aprod;
  unsigned short *parS;
  int *sorted, *lvlStart, *nlev;
  float *pOut;
};

__device__ __forceinline__ unsigned short bf16ru(float f) {
    unsigned u = __float_as_uint(f);
    u += 0x7fffu + ((u >> 16) & 1u);
    return (unsigned short)(u >> 16);
}

__device__ __forceinline__ void glds16(const void* g, void* l) {
    __builtin_amdgcn_global_load_lds((const __attribute__((address_space(1))) unsigned int*)g,
                                     (__attribute__((address_space(3))) unsigned int*)l, 16, 0, 0);
}

// poly gelu pair, fused bf16-addend unpack + bf16 trunc pack (|x|<~0.8 -> err<=1e-3)
__device__ __forceinline__ unsigned packpair(float2v a, unsigned c) {
    float2v cb;
    cb.x = __uint_as_float(c << 16);
    cb.y = __uint_as_float(c & 0xffff0000u);
    float2v x = a + cb;
    float2v t = x * x;
    float2v i = t * (-0.06649038f) + 0.39894228f;
    float2v p = x * i + 0.5f;
    float2v g = x * p;
    union { float2v f; unsigned u[2]; } gu; gu.f = g;
    return __builtin_amdgcn_perm(gu.u[1], gu.u[0], 0x07060302u);
}

// ================= prep0: pure streaming converts + misc =================

// fp32 KxN row-major chunk (16 k-rows at srcRow0) -> bf16 B-tile via LDS transpose
__device__ void bconv_f(const float* __restrict__ srcRow0, unsigned short* __restrict__ dst,
                        int N, int K16, int kbase, char* smc) {
    unsigned short* wl = (unsigned short*)smc;   // 16*N bf16
    int tid = threadIdx.x;
    int tot4 = 4 * N;   // 16*N/4 float4s
    for (int i4 = tid; i4 < tot4; i4 += 256) {
        float4 w = ((const float4*)srcRow0)[i4];
        ushort4 o;
        o.x = bf16ru(w.x); o.y = bf16ru(w.y); o.z = bf16ru(w.z); o.w = bf16ru(w.w);
        *(ushort4*)&wl[i4 * 4] = o;
    }
    __syncthreads();
    for (int i = tid; i < 2 * N; i += 256) {
        int kg = (i >= N) ? 1 : 0;
        int n = i - kg * N;
        int k0 = kbase + kg * 8;
        ushort4 o0, o1;
        o0.x = wl[(kg * 8 + 0) * N + n]; o0.y = wl[(kg * 8 + 1) * N + n];
        o0.z = wl[(kg * 8 + 2) * N + n]; o0.w = wl[(kg * 8 + 3) * N + n];
        o1.x = wl[(kg * 8 + 4) * N + n]; o1.y = wl[(kg * 8 + 5) * N + n];
        o1.z = wl[(kg * 8 + 6) * N + n]; o1.w = wl[(kg * 8 + 7) * N + n];
        size_t off = (size_t)(n >> 4) * K16 + (k0 >> 5) * 512 + ((k0 >> 3) & 3) * 128 + (n & 15) * 8;
        *(ushort4*)&dst[off]     = o0;
        *(ushort4*)&dst[off + 4] = o1;
    }
}

// fp32 MxK row-major chunk (16 rows at r0) -> bf16 A-tile (no transpose)
__device__ void aconv_f(const float* __restrict__ src, unsigned short* __restrict__ dst,
                        int r0, int K, int K16) {
    int tid = threadIdx.x;
    int Kq = K >> 2;
    for (int rl = 0; rl < 16; ++rl) {
        int row = r0 + rl;
        for (int i = tid; i < Kq; i += 256) {
            float4 w = ((const float4*)(src + (size_t)row * K))[i];
            ushort4 o;
            o.x = bf16ru(w.x); o.y = bf16ru(w.y); o.z = bf16ru(w.z); o.w = bf16ru(w.w);
            int k4 = i * 4;
            size_t off = (size_t)(row >> 4) * K16 + (k4 >> 5) * 512 + ((k4 >> 3) & 3) * 128
                       + (row & 15) * 8 + (k4 & 7);
            *(ushort4*)&dst[off] = o;
        }
    }
}

// t/v_clip 8 rows -> bf16 A-tile (M=128 K=768) + row 1/norm scales
__device__ void tcv_f(const P& a, int rel) {
    int sel = rel & 1, r8 = rel >> 1;
    const float* X = sel ? a.t_clip : a.v_clip;
    unsigned short* dst = a.tvbf + sel * 98304;
    int tid = threadIdx.x;
    int rl = tid >> 5, l = tid & 31;
    int b = r8 * 8 + rl;
    const float4* src = (const float4*)(X + (size_t)b * 768);
    float ss = 0.f;
#pragma unroll
    for (int j = 0; j < 6; ++j) {
        int i4 = l + j * 32;
        float4 w = src[i4];
        ss += w.x * w.x + w.y * w.y + w.z * w.z + w.w * w.w;
        ushort4 o;
        o.x = bf16ru(w.x); o.y = bf16ru(w.y); o.z = bf16ru(w.z); o.w = bf16ru(w.w);
        int k4 = i4 * 4;
        size_t off = (size_t)(b >> 4) * 12288 + (k4 >> 5) * 512 + ((k4 >> 3) & 3) * 128
                   + (b & 15) * 8 + (k4 & 7);
        *(ushort4*)&dst[off] = o;
    }
#pragma unroll
    for (int mk = 16; mk; mk >>= 1) ss += __shfl_xor(ss, mk);
    if (l == 0) a.sBuf[sel * 128 + b] = 1.0f / fmaxf(sqrtf(ss), 1e-12f);
}

// U,V -> B-tile K=256 N=128, LDS transpose. 16 blocks x 16 k-rows
__device__ void uvconv_f(const P& a, int blk, char* smc) {
    unsigned short* wl = (unsigned short*)smc;   // 16*128
    int kbase = blk * 16;
    int tid = threadIdx.x;
    for (int i = tid; i < 2048; i += 256) {
        int kl = i >> 7, n = i & 127;
        float v = (n < 64) ? a.U[(size_t)(kbase + kl) * 64 + n]
                           : a.V[(size_t)(kbase + kl) * 64 + (n - 64)];
        wl[kl * 128 + n] = bf16ru(v);
    }
    __syncthreads();
    {
        int i = tid;              // 256 = 2 kg x 128 n
        int kg = i >> 7, n = i & 127;
        int k0 = kbase + kg * 8;
        ushort4 o0, o1;
        o0.x = wl[(kg * 8 + 0) * 128 + n]; o0.y = wl[(kg * 8 + 1) * 128 + n];
        o0.z = wl[(kg * 8 + 2) * 128 + n]; o0.w = wl[(kg * 8 + 3) * 128 + n];
        o1.x = wl[(kg * 8 + 4) * 128 + n]; o1.y = wl[(kg * 8 + 5) * 128 + n];
        o1.z = wl[(kg * 8 + 6) * 128 + n]; o1.w = wl[(kg * 8 + 7) * 128 + n];
        size_t off = (size_t)(n >> 4) * 4096 + (k0 >> 5) * 512 + ((k0 >> 3) & 3) * 128 + (n & 15) * 8;
        *(ushort4*)&a.uvB[off]     = o0;
        *(ushort4*)&a.uvB[off + 4] = o1;
    }
}

// biasPM: [bp2|bm2] @ [U|V], 8 blocks x 32 outputs x 8 lanes
__device__ void biasPM_f(const P& a, int blk) {
    int tid = threadIdx.x;
    int o = blk * 32 + (tid >> 3), e = tid & 7;
    const float* bb = (o < 128) ? a.bp2 : a.bm2;
    int c = o & 127;
    const float* uv = (c < 64) ? (a.U + c) : (a.V + (c - 64));
    float acc = 0.f;
    for (int d = e * 32; d < e * 32 + 32; ++d)
        acc = fmaf(bb[d], uv[(size_t)d * 64], acc);
    acc += __shfl_xor(acc, 1);
    acc += __shfl_xor(acc, 2);
    acc += __shfl_xor(acc, 4);
    if (e == 0) a.biasPM[o] = acc;
}

// alpha -> per-node {parS (masked->1024), aprod}. 256 blocks
__device__ void alpha_f(const P& a, int blk) {
    int t = threadIdx.x, wv = t >> 6, lane = t & 63;
    int node = blk * 4 + wv;
    int slot = lane >> 3, e = lane & 7;
    int par = a.pid[node * 8 + slot];          // par==0 <=> masked
    const float4* qk = (const float4*)(a.concept_q + (size_t)node * 256);
    const float4* qp = (const float4*)(a.concept_q + (size_t)par * 256);
    float dq = 0, np = 0, ns = 0;
#pragma unroll
    for (int i = 0; i < 8; ++i) {
        float4 x = qp[e * 8 + i], y = qk[e * 8 + i];
        dq += x.x * y.x + x.y * y.y + x.z * y.z + x.w * y.w;
        np += x.x * x.x + x.y * x.y + x.z * x.z + x.w * x.w;
        ns += y.x * y.x + y.y * y.y + y.z * y.z + y.w * y.w;
    }
#pragma unroll
    for (int mk = 1; mk <= 4; mk <<= 1) {
        dq += __shfl_xor(dq, mk); np += __shfl_xor(np, mk); ns += __shfl_xor(ns, mk);
    }
    float score = dq / fmaxf(sqrtf(np) * sqrtf(ns), 1e-24f);
    float sc[8]; int pv[8];
#pragma unroll
    for (int s = 0; s < 8; ++s) { sc[s] = __shfl(score, s * 8); pv[s] = __shfl(par, s * 8); }
    float mx = -1e30f;
#pragma unroll
    for (int s = 0; s < 8; ++s) if (pv[s] != 0) mx = fmaxf(mx, sc[s]);
    float sum = 0.f;
#pragma unroll
    for (int s = 0; s < 8; ++s) sum += (pv[s] != 0) ? expf(sc[s] - mx) : 0.0f;
    float ap = 1.0f;
#pragma unroll
    for (int s = 0; s < 8; ++s) if (pv[s] != 0) ap *= expf(sc[s] - mx) / sum;
    if (lane == 0) a.aprod[node] = ap;
    if (e == 0) a.parS[node * 8 + slot] = (par != 0) ? (unsigned short)par : (unsigned short)1024;
}

// async Jacobi levels + counting sort by level. 1 block
__device__ void levels_f(const P& a, int* smemI) {
    volatile int* lvl = smemI;
    int* cnt  = smemI + 1024;
    int* ofs  = smemI + 2048;
    int* ping = smemI + 3072;
    int* pong = smemI + 3328;
    int* mflag = smemI + 3584;
    int t = threadIdx.x;
    int par[4][8]; int hasm[4];
#pragma unroll
    for (int r = 0; r < 4; ++r) {
        int n = t * 4 + r, h = 0;
#pragma unroll
        for (int s = 0; s < 8; ++s) { int p = a.pid[n * 8 + s]; par[r][s] = p; h |= (p != 0); }
        hasm[r] = h; lvl[n] = 0;
    }
    if (t == 0) mflag[1] = 0;
    __syncthreads();
    for (int round = 0; round < 200; ++round) {
        if (t == 0) mflag[0] = 0;
        __syncthreads();
        int ch = 0;
        for (int sub = 0; sub < 8; ++sub) {
#pragma unroll
            for (int r = 0; r < 4; ++r) {
                if (!hasm[r]) continue;
                int mx = 0;
#pragma unroll
                for (int s = 0; s < 8; ++s) { int p = par[r][s]; if (p) mx = max(mx, lvl[p]); }
                int nl = mx + 1;
                if (nl > lvl[t * 4 + r]) { lvl[t * 4 + r] = nl; ch = 1; }
            }
        }
        if (ch) mflag[0] = 1;
        __syncthreads();
        if (mflag[0] == 0) break;
    }
    int lm = 0;
    for (int r = 0; r < 4; ++r) lm = max(lm, lvl[t * 4 + r]);
    atomicMax(&mflag[1], lm);
    for (int r = 0; r < 4; ++r) cnt[t * 4 + r] = 0;
    __syncthreads();
    for (int r = 0; r < 4; ++r) atomicAdd(&cnt[lvl[t * 4 + r]], 1);
    __syncthreads();
    int c0 = cnt[t * 4], c1 = cnt[t * 4 + 1], c2 = cnt[t * 4 + 2], c3 = cnt[t * 4 + 3];
    ping[t] = c0 + c1 + c2 + c3;
    __syncthreads();
    int* src = ping; int* dst = pong;
    for (int off = 1; off < 256; off <<= 1) {
        int v = src[t];
        if (t >= off) v += src[t - off];
        dst[t] = v;
        __syncthreads();
        int* tmp = src; src = dst; dst = tmp;
    }
    int excl = (t == 0) ? 0 : src[t - 1];
    ofs[t * 4] = excl; ofs[t * 4 + 1] = excl + c0;
    ofs[t * 4 + 2] = excl + c0 + c1; ofs[t * 4 + 3] = excl + c0 + c1 + c2;
#pragma unroll
    for (int r = 0; r < 4; ++r) a.lvlStart[t * 4 + r] = ofs[t * 4 + r];
    if (t == 0) { a.lvlStart[1024] = 1024; a.nlev[0] = mflag[1] + 1; }
    __syncthreads();
    for (int r = 0; r < 4; ++r) {
        int n = t * 4 + r;
        int pos = atomicAdd(&ofs[lvl[n]], 1);
        a.sorted[pos] = n;
    }
}

__global__ void __launch_bounds__(256) prep0_kernel(P a) {
    __shared__ char smem[16640];
    int bid = blockIdx.x;
    if (bid == 0) { levels_f(a, (int*)smem); return; }
    bid -= 1;
    if (bid < 96) {   // W1 split convert
        int mat = bid & 1, rb = bid >> 1;
        int r0 = rb * 16;
        const float* W1 = mat ? a.Wm1 : a.Wp1;
        if (r0 < 512) bconv_f(W1 + (size_t)r0 * 512, mat ? a.w1upM : a.w1upP, 512, 8192, r0, smem);
        else          bconv_f(W1 + (size_t)r0 * 512, mat ? a.w1lowM : a.w1lowP, 512, 4096, r0 - 512, smem);
        return;
    }
    bid -= 96;
    if (bid < 96) {   // Wt/Wv
        int sel = bid & 1, ch = bid >> 1;
        bconv_f((sel ? a.Wt : a.Wv) + (size_t)ch * 16 * 256, a.wtvB + sel * 196608, 256, 12288, ch * 16, smem);
        return;
    }
    bid -= 96;
    if (bid < 24) { bconv_f(a.Wc + (size_t)bid * 16 * 256, a.wcB, 256, 6144, bid * 16, smem); return; }
    bid -= 24;
    if (bid < 24) { bconv_f(a.Wg1 + (size_t)bid * 16 * 64, a.wg1B, 64, 6144, bid * 16, smem); return; }
    bid -= 24;
    if (bid < 4) { bconv_f(a.Wg2 + (size_t)bid * 16 * 64, a.wg2B, 64, 1024, bid * 16, smem); return; }
    bid -= 4;
    if (bid < 64) {   // W2p/m A-tiles
        int mat = bid & 1, ch = bid >> 1;
        aconv_f(mat ? a.Wm2 : a.Wp2, a.w2bf + mat * 131072, ch * 16, 256, 4096);
        return;
    }
    bid -= 64;
    if (bid < 16) { uvconv_f(a, bid, smem); return; }
    bid -= 16;
    if (bid < 32) { tcv_f(a, bid); return; }
    bid -= 32;
    if (bid < 64) { aconv_f(a.sbert, a.sbbf, bid * 16, 384, 6144); return; }
    bid -= 64;
    if (bid < 256) { alpha_f(a, bid); return; }
    bid -= 256;
    if (bid < 8) { biasPM_f(a, bid); return; }
    bid -= 8;
    { int k = bid * 256 + threadIdx.x; a.tau[k] = 1.0f / (1.0f + expf(-a.tau_logits[k])); }
}

// ================= MFMA 64x64 GEMM helper =================
__device__ __forceinline__ void gemm64(const unsigned short* A, const unsigned short* B,
                                       int K16A, int K16B, int nsteps,
                                       float4v acc[4], int m, int quad) {
    const unsigned short* Ab = A + quad * 128 + m * 8;
    const unsigned short* Bb = B + quad * 128 + m * 8;
    for (int s = 0; s < nsteps; ++s) {
        short8 af = *(const short8*)(Ab + s * 512);
#pragma unroll
        for (int nt = 0; nt < 4; ++nt) {
            short8 bf = *(const short8*)(Bb + (size_t)nt * K16B + s * 512);
            acc[nt] = __builtin_amdgcn_mfma_f32_16x16x32_bf16(af, bf, acc[nt], 0, 0, 0);
        }
    }
}

// ================= prep1: first-stage GEMMs =================
__global__ void __launch_bounds__(256) prep1_kernel(P a) {
    int bid = blockIdx.x;
    int tid = threadIdx.x;
    int wv = tid >> 6, lane = tid & 63;
    int m = lane & 15, quad = lane >> 4;
    float4v acc[4];
#pragma unroll
    for (int i = 0; i < 4; ++i) acc[i] = (float4v)0.0f;

    if (bid < 16) {
        // tv-proj: sel GEMM M=128 K=768 N=256; epilogue scale+bias -> vtbf A-tile
        int sel = bid & 1, mt = (bid >> 1) & 1, ntile = bid >> 2;
        const unsigned short* A = a.tvbf + sel * 98304 + (size_t)(mt * 4 + wv) * 12288;
        const unsigned short* B = a.wtvB + sel * 196608 + (size_t)(ntile * 4) * 12288;
        gemm64(A, B, 12288, 12288, 24, acc, m, quad);
        const float* bias = sel ? a.bt : a.bv;
#pragma unroll
        for (int nt = 0; nt < 4; ++nt) {
            int col = ntile * 64 + nt * 16 + m;
            int vtcol = sel * 256 + col;
            float bb = bias[col];
#pragma unroll
            for (int r = 0; r < 4; ++r) {
                int row = mt * 64 + wv * 16 + quad * 4 + r;
                float val = acc[nt][r] * a.sBuf[sel * 128 + row] + bb;
                size_t off = (size_t)(row >> 4) * 8192 + (vtcol >> 5) * 512
                           + ((vtcol >> 3) & 3) * 128 + (row & 15) * 8 + (vtcol & 7);
                a.vtbf[off] = bf16ru(val);
            }
        }
        return;
    }
    bid -= 16;
    if (bid < 64) {
        // d-proj: M=1024 K=384 N=256 -> dbf A-tile (+bc)
        int mt = bid & 15, ntile = bid >> 4;
        const unsigned short* A = a.sbbf + (size_t)(mt * 4 + wv) * 6144;
        const unsigned short* B = a.wcB + (size_t)(ntile * 4) * 6144;
        gemm64(A, B, 6144, 6144, 12, acc, m, quad);
#pragma unroll
        for (int nt = 0; nt < 4; ++nt) {
            int col = ntile * 64 + nt * 16 + m;
            float bb = a.bc[col];
#pragma unroll
            for (int r = 0; r < 4; ++r) {
                int row = mt * 64 + wv * 16 + quad * 4 + r;
                size_t off = (size_t)(row >> 4) * 4096 + (col >> 5) * 512
                           + ((col >> 3) & 3) * 128 + (row & 15) * 8 + (col & 7);
                a.dbf[off] = bf16ru(acc[nt][r] + bb);
            }
        }
        return;
    }
    bid -= 64;
    if (bid < 16) {
        // gw stage1: M=1024 K=384 N=64 -> ghbf = erf-gelu(acc+bg1)
        int mt = bid;
        const unsigned short* A = a.sbbf + (size_t)(mt * 4 + wv) * 6144;
        gemm64(A, a.wg1B, 6144, 6144, 12, acc, m, quad);
#pragma unroll
        for (int nt = 0; nt < 4; ++nt) {
            int col = nt * 16 + m;
            float bb = a.bg1[col];
#pragma unroll
            for (int r = 0; r < 4; ++r) {
                int row = mt * 64 + wv * 16 + quad * 4 + r;
                float x = acc[nt][r] + bb;
                float g = 0.5f * x * (1.0f + erff(x * 0.7071067811865475f));
                size_t off = (size_t)(row >> 4) * 1024 + (col >> 5) * 512
                           + ((col >> 3) & 3) * 128 + (row & 15) * 8 + (col & 7);
                a.ghbf[off] = bf16ru(g);
            }
        }
        return;
    }
    bid -= 16;
    {
        // packW: W2 @ [U|V], M=512 K=256 N=128 -> W-tile
        int mat = bid & 1, mt = (bid >> 1) & 7, ntile = bid >> 4;
        const unsigned short* A = a.w2bf + mat * 131072 + (size_t)(mt * 4 + wv) * 4096;
        const unsigned short* B = a.uvB + (size_t)(ntile * 4) * 4096;
        gemm64(A, B, 4096, 4096, 8, acc, m, quad);
        unsigned short* outP = mat ? a.Wmk : a.Wpk;
#pragma unroll
        for (int nt = 0; nt < 4; ++nt) {
            int c = ntile * 64 + nt * 16 + m;
#pragma unroll
            for (int r = 0; r < 4; ++r) {
                int j = mt * 64 + wv * 16 + quad * 4 + r;
                size_t o = (size_t)(j >> 5) * 4096 + (c >> 4) * 512 + ((j >> 3) & 3) * 128
                         + (c & 15) * 8 + (j & 7);
                outP[o] = bf16ru(acc[nt][r]);
            }
        }
    }
}

// ================= prep2: second-stage GEMMs =================
__global__ void __launch_bounds__(256) prep2_kernel(P a) {
    int bid = blockIdx.x;
    int tid = threadIdx.x;
    int wv = tid >> 6, lane = tid & 63;
    int m = lane & 15, quad = lane >> 4;
    if (bid < 256) {
        // C = d @ W1low : M=1024 K=256 N=512, x2 mats
        int mat = bid & 1, mt = (bid >> 1) & 15, ntile = bid >> 5;
        const unsigned short* A = a.dbf + (size_t)(mt * 4 + wv) * 4096 + quad * 128 + m * 8;
        const unsigned short* B = (mat ? a.w1lowM : a.w1lowP) + (size_t)quad * 128 + m * 8;
        unsigned short* Ct = mat ? a.Ctm : a.Ctp;
        float4v acc[4];
#pragma unroll
        for (int i = 0; i < 4; ++i) acc[i] = (float4v)0.0f;
        for (int s = 0; s < 8; ++s) {
            short8 af = *(const short8*)(A + s * 512);
#pragma unroll
            for (int nt = 0; nt < 4; ++nt) {
                short8 bf = *(const short8*)(B + (size_t)(ntile * 4 + nt) * 4096 + s * 512);
                acc[nt] = __builtin_amdgcn_mfma_f32_16x16x32_bf16(af, bf, acc[nt], 0, 0, 0);
            }
        }
        int rowg = mt * 4 + wv;
        int rl = quad * 4;
#pragma unroll
        for (int nt = 0; nt < 4; ++nt) {
            int j = ntile * 64 + nt * 16 + m;
            size_t base = (size_t)rowg * 8192 + (j >> 5) * 512 + ((j >> 3) & 3) * 128 + (j & 7);
#pragma unroll
            for (int rr = 0; rr < 4; ++rr)
                Ct[base + (rl + rr) * 8] = bf16ru(acc[nt][rr]);
        }
        return;
    }
    bid -= 256;
    if (bid < 32) {
        // Ap/Am = vt @ W1up + b1 : M=128 K=512 N=512, x2 mats
        int mat = bid & 1, mt = (bid >> 1) & 1, ntile = bid >> 2;
        const unsigned short* A = a.vtbf + (size_t)(mt * 4 + wv) * 8192 + quad * 128 + m * 8;
        const unsigned short* B = (mat ? a.w1upM : a.w1upP) + (size_t)quad * 128 + m * 8;
        const float* bias = mat ? a.bm1 : a.bp1;
        float* out = mat ? a.Am : a.Ap;
        float4v acc[4];
#pragma unroll
        for (int i = 0; i < 4; ++i) acc[i] = (float4v)0.0f;
        for (int s = 0; s < 16; ++s) {
            short8 af = *(const short8*)(A + s * 512);
#pragma unroll
            for (int nt = 0; nt < 4; ++nt) {
                short8 bf = *(const short8*)(B + (size_t)(ntile * 4 + nt) * 8192 + s * 512);
                acc[nt] = __builtin_amdgcn_mfma_f32_16x16x32_bf16(af, bf, acc[nt], 0, 0, 0);
            }
        }
        int b0r = mt * 64 + wv * 16 + quad * 4;
#pragma unroll
        for (int nt = 0; nt < 4; ++nt) {
            int j = ntile * 64 + nt * 16 + m;
            float bb = bias[j];
#pragma unroll
            for (int rr = 0; rr < 4; ++rr)
                out[(size_t)(b0r + rr) * 512 + j] = acc[nt][rr] + bb;
        }
        return;
    }
    bid -= 32;
    {
        // gw stage2: M=1024 K=64 N=64: (ghbf@Wg2 + bg2) * w_out -> gw fp32
        int mt = bid;
        const unsigned short* A = a.ghbf + (size_t)(mt * 4 + wv) * 1024 + quad * 128 + m * 8;
        const unsigned short* B = a.wg2B + (size_t)quad * 128 + m * 8;
        float4v acc[4];
#pragma unroll
        for (int i = 0; i < 4; ++i) acc[i] = (float4v)0.0f;
        for (int s = 0; s < 2; ++s) {
            short8 af = *(const short8*)(A + s * 512);
#pragma unroll
            for (int nt = 0; nt < 4; ++nt) {
                short8 bf = *(const short8*)(B + (size_t)nt * 1024 + s * 512);
                acc[nt] = __builtin_amdgcn_mfma_f32_16x16x32_bf16(af, bf, acc[nt], 0, 0, 0);
            }
        }
#pragma unroll
        for (int nt = 0; nt < 4; ++nt) {
            int col = nt * 16 + m;
            float bb = a.bg2[col];
#pragma unroll
            for (int r = 0; r < 4; ++r) {
                int k = mt * 64 + wv * 16 + quad * 4 + r;
                a.gw[(size_t)k * 64 + col] = (acc[nt][r] + bb) * a.w_out[(size_t)k * 64 + col];
            }
        }
    }
}

// ========== main: LDS-staged (global_load_lds) dbuf W, 4 batches, P/M wave-split ==========
__global__ void __launch_bounds__(512, 2) main_kernel(P a) {
    __shared__ float apL[4096];
    __shared__ char wbuf[2][16384];
    int tid = threadIdx.x;
    int wv2 = tid >> 6, lane = tid & 63;
    int mat = wv2 >> 2, sub = wv2 & 3;
    int m = lane & 15, quad = lane >> 4;
    int b0 = (blockIdx.x >> 4) * 4;
    int k0 = (blockIdx.x & 15) << 6;

    for (int i = tid; i < 1024; i += 512) {
        int arr = i >> 7, off = i & 127;
        const float* src = ((arr >> 2) ? a.Am : a.Ap) + (size_t)(b0 + (arr & 3)) * 512;
        ((float4*)apL)[i] = ((const float4*)src)[off];
    }

    const char* wg = ((wv2 < 4) ? (const char*)a.Wpk : (const char*)a.Wmk)
                   + (wv2 & 3) * 2048 + lane * 16;
    char* wl0 = &wbuf[0][wv2 * 2048];
    char* wl1 = &wbuf[1][wv2 * 2048];

    const unsigned short* Ct = mat ? a.Ctm : a.Ctp;
    const float* aL = apL + mat * 2048;
    int kt = (k0 >> 4) + sub;
    const char* ctB = (const char*)Ct + (size_t)kt * 16384 + quad * 256 + m * 16;

    float4v acc[4][8];
#pragma unroll
    for (int b = 0; b < 4; ++b)
#pragma unroll
        for (int i = 0; i < 8; ++i) acc[b][i] = (float4v)0.0f;

    glds16(wg, wl0);
    glds16(wg + 1024, wl0 + 1024);
    uint4 crN = *(const uint4*)(ctB);
    __syncthreads();

    for (int n = 0; n < 16; ++n) {
        if (n < 15) {
            char* dst = ((n + 1) & 1) ? wl1 : wl0;
            glds16(wg + (n + 1) * 8192, dst);
            glds16(wg + (n + 1) * 8192 + 1024, dst + 1024);
        }
        uint4 cr = crN;
        if (n < 15) crN = *(const uint4*)(ctB + (n + 1) * 1024);
        union { uint4 u; short8 s; } fa[4];
        const float* aj = aL + n * 32 + quad * 8;
#pragma unroll
        for (int b = 0; b < 4; ++b) {
            float4v x0 = *(const float4v*)(aj + b * 512);
            float4v x1 = *(const float4v*)(aj + b * 512 + 4);
            float2v v;
            v.x = x0[0]; v.y = x0[1]; fa[b].u.x = packpair(v, cr.x);
            v.x = x0[2]; v.y = x0[3]; fa[b].u.y = packpair(v, cr.y);
            v.x = x1[0]; v.y = x1[1]; fa[b].u.z = packpair(v, cr.z);
            v.x = x1[2]; v.y = x1[3]; fa[b].u.w = packpair(v, cr.w);
        }
        const char* wB = &wbuf[n & 1][0] + mat * 8192 + quad * 256 + m * 16;
#pragma unroll
        for (int nt = 0; nt < 8; ++nt) {
            short8 wf = *(const short8*)(wB + nt * 1024);
            acc[0][nt] = __builtin_amdgcn_mfma_f32_16x16x32_bf16(fa[0].s, wf, acc[0][nt], 0, 0, 0);
            acc[1][nt] = __builtin_amdgcn_mfma_f32_16x16x32_bf16(fa[1].s, wf, acc[1][nt], 0, 0, 0);
            acc[2][nt] = __builtin_amdgcn_mfma_f32_16x16x32_bf16(fa[2].s, wf, acc[2][nt], 0, 0, 0);
            acc[3][nt] = __builtin_amdgcn_mfma_f32_16x16x32_bf16(fa[3].s, wf, acc[3][nt], 0, 0, 0);
        }
        __syncthreads();
    }

    float* xbuf = (float*)wbuf;
    int kk[4]; float tv[4];
#pragma unroll
    for (int r = 0; r < 4; ++r) { kk[r] = k0 + sub * 16 + quad * 4 + r; tv[r] = a.tau[kk[r]]; }
    float lsum[4][4] = {};
#pragma unroll
    for (int t4 = 0; t4 < 4; ++t4) {
        __syncthreads();
        if (mat == 1) {
#pragma unroll
            for (int b = 0; b < 4; ++b) {
                int slot = (sub * 4 + b) * 64 + lane;
#pragma unroll
                for (int r = 0; r < 4; ++r) {
                    xbuf[r * 1024 + slot]       = acc[b][t4][r];
                    xbuf[(r + 4) * 1024 + slot] = acc[b][t4 + 4][r];
                }
            }
        }
        __syncthreads();
        if (mat == 0) {
            int cU = t4 * 16 + m, cV = cU + 64;
            float bPu = a.biasPM[cU], bMu = a.biasPM[128 + cU];
            float bPv = a.biasPM[cV], bMv = a.biasPM[128 + cV];
#pragma unroll
            for (int b = 0; b < 4; ++b) {
                int slot = (sub * 4 + b) * 64 + lane;
#pragma unroll
                for (int r = 0; r < 4; ++r) {
                    float g = a.gw[(size_t)kk[r] * 64 + cU];
                    float u  = tv[r] * (acc[b][t4][r] + bPu)
                             + (1.0f - tv[r]) * (xbuf[r * 1024 + slot] + bMu);
                    float vx = tv[r] * (acc[b][t4 + 4][r] + bPv)
                             + (1.0f - tv[r]) * (xbuf[(r + 4) * 1024 + slot] + bMv);
                    lsum[b][r] = fmaf(u * vx, g, lsum[b][r]);
                }
            }
        }
    }
    if (mat == 0) {
#pragma unroll
        for (int r = 0; r < 4; ++r) {
            float bo = a.b_out[kk[r]];
#pragma unroll
            for (int b = 0; b < 4; ++b) {
                float s = lsum[b][r];
                s += __shfl_xor(s, 1); s += __shfl_xor(s, 2); s += __shfl_xor(s, 4); s += __shfl_xor(s, 8);
                if (m == 0)
                    a.pOut[(size_t)(b0 + b) * 1024 + kk[r]] = 1.0f / (1.0f + expf(-(s + bo)));
            }
        }
    }
}

// ========== scan: one wave per batch, graph state in LDS, no level barriers ==========
#define PH_STRIDE 1056
__global__ void __launch_bounds__(256) scan_kernel(P a) {
    __shared__ float ph[4 * PH_STRIDE];
    __shared__ float aprodL[1024];
    __shared__ unsigned short parL[8192];
    __shared__ short sortedL[1024];
    __shared__ int lvlStartL[1025];
    int t = threadIdx.x;
    int b0 = blockIdx.x * 4;
    for (int i = t; i < 1024; i += 256) ((uint4*)parL)[i] = ((const uint4*)a.parS)[i];
    for (int i = t; i < 1024; i += 256) {
        aprodL[i] = a.aprod[i];
        sortedL[i] = (short)a.sorted[i];
        lvlStartL[i] = a.lvlStart[i];
    }
    if (t == 0) lvlStartL[1024] = 1024;
    for (int i = t; i < 4096; i += 256) {
        int bb = i >> 10, k = i & 1023;
        ph[bb * PH_STRIDE + k] = a.pOut[(size_t)(b0 + bb) * 1024 + k];
    }
    if (t < 4) ph[t * PH_STRIDE + 1024] = 1.0f;
    __syncthreads();
    int nlev = a.nlev[0];
    int w = t >> 6, lane = t & 63;
    float* myph = ph + w * PH_STRIDE;
    for (int L = 1; L < nlev; ++L) {
        int s0 = lvlStartL[L], s1 = lvlStartL[L + 1];
        for (int i = s0 + lane; i < s1; i += 64) {
            int node = sortedL[i];
            ushort4 pA = *(const ushort4*)&parL[node * 8];
            ushort4 pB = *(const ushort4*)&parL[node * 8 + 4];
            float prod = aprodL[node];
            prod *= myph[pA.x] * myph[pA.y];
            prod *= myph[pA.z] * myph[pA.w];
            prod *= myph[pB.x] * myph[pB.y];
            prod *= myph[pB.z] * myph[pB.w];
            myph[node] = fmaf(0.35f, myph[node], 0.65f * prod);
        }
    }
    __syncthreads();
    for (int i = t; i < 4096; i += 256) {
        int bb = i >> 10, k = i & 1023;
        a.pOut[(size_t)(b0 + bb) * 1024 + k] = ph[bb * PH_STRIDE + k];
    }
}

extern "C" void kernel_launch(void* const* d_in, const int* in_sizes, int n_in,
                              void* d_out, int out_size, void* d_ws, size_t ws_size,
                              hipStream_t stream) {
    P a;
    a.t_clip = (const float*)d_in[0];
    a.v_clip = (const float*)d_in[1];
    a.sbert  = (const float*)d_in[2];
    a.Wt  = (const float*)d_in[3];  a.bt  = (const float*)d_in[4];
    a.Wv  = (const float*)d_in[5];  a.bv  = (const float*)d_in[6];
    a.Wc  = (const float*)d_in[7];  a.bc  = (const float*)d_in[8];
    a.Wp1 = (const float*)d_in[9];  a.bp1 = (const float*)d_in[10];
    a.Wp2 = (const float*)d_in[11]; a.bp2 = (const float*)d_in[12];
    a.Wm1 = (const float*)d_in[13]; a.bm1 = (const float*)d_in[14];
    a.Wm2 = (const float*)d_in[15]; a.bm2 = (const float*)d_in[16];
    a.tau_logits = (const float*)d_in[17];
    a.U   = (const float*)d_in[18]; a.V   = (const float*)d_in[19];
    a.Wg1 = (const float*)d_in[20]; a.bg1 = (const float*)d_in[21];
    a.Wg2 = (const float*)d_in[22]; a.bg2 = (const float*)d_in[23];
    a.w_out = (const float*)d_in[24]; a.b_out = (const float*)d_in[25];
    a.concept_q = (const float*)d_in[26];
    a.pid = (const int*)d_in[27];
    // d_in[28] parents_mask unused (par==0 <=> masked); d_in[29] order unused

    char* w = (char*)d_ws;
    // region X (conversion tiles, dead after prep1) aliased with Ct (written in prep2)
    a.Ctp  = (unsigned short*)(w + 0);             // 1 MB
    a.Ctm  = (unsigned short*)(w + 1048576);       // 1 MB
    a.tvbf = (unsigned short*)(w + 0);             // 384 KB
    a.sbbf = (unsigned short*)(w + 393216);        // 768 KB
    a.wtvB = (unsigned short*)(w + 1179648);       // 768 KB
    a.wcB  = (unsigned short*)(w + 1966080);       // 192 KB -> ends 2162688
    a.w1upP  = (unsigned short*)(w + 2162688);
    a.w1upM  = (unsigned short*)(w + 2686976);
    a.w1lowP = (unsigned short*)(w + 3211264);
    a.w1lowM = (unsigned short*)(w + 3473408);
    a.wg1B   = (unsigned short*)(w + 3735552);
    a.wg2B   = (unsigned short*)(w + 3784704);
    a.w2bf   = (unsigned short*)(w + 3792896);
    a.uvB    = (unsigned short*)(w + 4317184);
    a.vtbf   = (unsigned short*)(w + 4382720);
    a.dbf    = (unsigned short*)(w + 4513792);
    a.ghbf   = (unsigned short*)(w + 5038080);
    a.Wpk    = (unsigned short*)(w + 5169152);
    a.Wmk    = (unsigned short*)(w + 5300224);
    a.Ap     = (float*)(w + 5431296);
    a.Am     = (float*)(w + 5693440);
    a.biasPM = (float*)(w + 5955584);
    a.tau    = (float*)(w + 5956608);
    a.gw     = (float*)(w + 5960704);
    a.sBuf   = (float*)(w + 6222848);
    a.parS   = (unsigned short*)(w + 6223872);
    a.aprod  = (float*)(w + 6240256);
    a.sorted = (int*)(w + 6244352);
    a.lvlStart = (int*)(w + 6248448);
    a.nlev     = (int*)(w + 6252672);
    a.pOut = (float*)d_out;

    prep0_kernel<<<689, 256, 0, stream>>>(a);
    prep1_kernel<<<128, 256, 0, stream>>>(a);
    prep2_kernel<<<304, 256, 0, stream>>>(a);
    main_kernel<<<512, 512, 0, stream>>>(a);
    scan_kernel<<<32, 256, 0, stream>>>(a);
}

// Round 9
// 246.061 us; speedup vs baseline: 1.1241x; 1.1241x over previous
//
#include <hip/hip_runtime.h>
#include <math.h>

typedef __attribute__((ext_vector_type(8))) short short8;
typedef __attribute__((ext_vector_type(4))) float float4v;
typedef __attribute__((ext_vector_type(2))) float float2v;

struct P {
  const float *t_clip, *v_clip, *sbert;
  const float *Wt, *bt, *Wv, *bv, *Wc, *bc;
  const float *Wp1, *bp1, *Wp2, *bp2, *Wm1, *bm1, *Wm2, *bm2;
  const float *tau_logits, *U, *V, *Wg1, *bg1, *Wg2, *bg2, *w_out, *b_out, *concept_q;
  const int *pid;
  unsigned short *tvbf;             // A M=128 K=768, x2 (sel: 0=v,1=t)
  unsigned short *sbbf;             // A M=1024 K=384
  unsigned short *wtvB;             // B K=768 N=256, x2 (sel)
  unsigned short *wcB;              // B K=384 N=256
  unsigned short *wg1B;             // B K=384 N=64
  unsigned short *wg2B;             // B K=64 N=64
  unsigned short *w2bf;             // A M=512 K=256, x2 (mat)
  unsigned short *uvB;              // B K=256 N=128 ([U|V])
  unsigned short *w1upP, *w1upM;    // B K=512 N=512
  unsigned short *w1lowP, *w1lowM;  // B K=256 N=512
  unsigned short *vtbf;             // A M=128 K=512
  unsigned short *dbf;              // A M=1024 K=256
  unsigned short *ghbf;             // A M=1024 K=64
  unsigned short *Ctp, *Ctm;        // acts addend, tiled: byte = kt*16384 + n*1024 + quad*256 + m*16
  unsigned short *Wpk, *Wmk;        // W-tile: (j>>5)*4096+(c>>4)*512+((j>>3)&3)*128+(c&15)*8+(j&7)
  float *Ap, *Am;
  float *sBuf, *biasPM, *tau, *gw, *aprod;
  unsigned short *parS;
  int *sorted, *lvlStart, *nlev;
  float *pOut;
};

__device__ __forceinline__ unsigned short bf16ru(float f) {
    unsigned u = __float_as_uint(f);
    u += 0x7fffu + ((u >> 16) & 1u);
    return (unsigned short)(u >> 16);
}

__device__ __forceinline__ void glds16(const void* g, void* l) {
    __builtin_amdgcn_global_load_lds((const __attribute__((address_space(1))) unsigned int*)g,
                                     (__attribute__((address_space(3))) unsigned int*)l, 16, 0, 0);
}

// poly gelu pair, fused bf16-addend unpack + bf16 trunc pack (|x|<~0.8 -> err<=1e-3)
__device__ __forceinline__ unsigned packpair(float2v a, unsigned c) {
    float2v cb;
    cb.x = __uint_as_float(c << 16);
    cb.y = __uint_as_float(c & 0xffff0000u);
    float2v x = a + cb;
    float2v t = x * x;
    float2v i = t * (-0.06649038f) + 0.39894228f;
    float2v p = x * i + 0.5f;
    float2v g = x * p;
    union { float2v f; unsigned u[2]; } gu; gu.f = g;
    return __builtin_amdgcn_perm(gu.u[1], gu.u[0], 0x07060302u);
}

// ================= prep0: pure streaming converts + misc =================

// fp32 KxN row-major chunk (16 k-rows at srcRow0) -> bf16 B-tile via LDS transpose
__device__ void bconv_f(const float* __restrict__ srcRow0, unsigned short* __restrict__ dst,
                        int N, int K16, int kbase, char* smc) {
    unsigned short* wl = (unsigned short*)smc;   // 16*N bf16
    int tid = threadIdx.x;
    int tot4 = 4 * N;
    for (int i4 = tid; i4 < tot4; i4 += 256) {
        float4 w = ((const float4*)srcRow0)[i4];
        ushort4 o;
        o.x = bf16ru(w.x); o.y = bf16ru(w.y); o.z = bf16ru(w.z); o.w = bf16ru(w.w);
        *(ushort4*)&wl[i4 * 4] = o;
    }
    __syncthreads();
    for (int i = tid; i < 2 * N; i += 256) {
        int kg = (i >= N) ? 1 : 0;
        int n = i - kg * N;
        int k0 = kbase + kg * 8;
        ushort4 o0, o1;
        o0.x = wl[(kg * 8 + 0) * N + n]; o0.y = wl[(kg * 8 + 1) * N + n];
        o0.z = wl[(kg * 8 + 2) * N + n]; o0.w = wl[(kg * 8 + 3) * N + n];
        o1.x = wl[(kg * 8 + 4) * N + n]; o1.y = wl[(kg * 8 + 5) * N + n];
        o1.z = wl[(kg * 8 + 6) * N + n]; o1.w = wl[(kg * 8 + 7) * N + n];
        size_t off = (size_t)(n >> 4) * K16 + (k0 >> 5) * 512 + ((k0 >> 3) & 3) * 128 + (n & 15) * 8;
        *(ushort4*)&dst[off]     = o0;
        *(ushort4*)&dst[off + 4] = o1;
    }
}

// fp32 MxK row-major chunk (16 rows at r0) -> bf16 A-tile (no transpose)
__device__ void aconv_f(const float* __restrict__ src, unsigned short* __restrict__ dst,
                        int r0, int K, int K16) {
    int tid = threadIdx.x;
    int Kq = K >> 2;
    for (int rl = 0; rl < 16; ++rl) {
        int row = r0 + rl;
        for (int i = tid; i < Kq; i += 256) {
            float4 w = ((const float4*)(src + (size_t)row * K))[i];
            ushort4 o;
            o.x = bf16ru(w.x); o.y = bf16ru(w.y); o.z = bf16ru(w.z); o.w = bf16ru(w.w);
            int k4 = i * 4;
            size_t off = (size_t)(row >> 4) * K16 + (k4 >> 5) * 512 + ((k4 >> 3) & 3) * 128
                       + (row & 15) * 8 + (k4 & 7);
            *(ushort4*)&dst[off] = o;
        }
    }
}

// t/v_clip 8 rows -> bf16 A-tile (M=128 K=768) + row 1/norm scales
__device__ void tcv_f(const P& a, int rel) {
    int sel = rel & 1, r8 = rel >> 1;
    const float* X = sel ? a.t_clip : a.v_clip;
    unsigned short* dst = a.tvbf + sel * 98304;
    int tid = threadIdx.x;
    int rl = tid >> 5, l = tid & 31;
    int b = r8 * 8 + rl;
    const float4* src = (const float4*)(X + (size_t)b * 768);
    float ss = 0.f;
#pragma unroll
    for (int j = 0; j < 6; ++j) {
        int i4 = l + j * 32;
        float4 w = src[i4];
        ss += w.x * w.x + w.y * w.y + w.z * w.z + w.w * w.w;
        ushort4 o;
        o.x = bf16ru(w.x); o.y = bf16ru(w.y); o.z = bf16ru(w.z); o.w = bf16ru(w.w);
        int k4 = i4 * 4;
        size_t off = (size_t)(b >> 4) * 12288 + (k4 >> 5) * 512 + ((k4 >> 3) & 3) * 128
                   + (b & 15) * 8 + (k4 & 7);
        *(ushort4*)&dst[off] = o;
    }
#pragma unroll
    for (int mk = 16; mk; mk >>= 1) ss += __shfl_xor(ss, mk);
    if (l == 0) a.sBuf[sel * 128 + b] = 1.0f / fmaxf(sqrtf(ss), 1e-12f);
}

// U,V -> B-tile K=256 N=128, LDS transpose. 16 blocks x 16 k-rows
__device__ void uvconv_f(const P& a, int blk, char* smc) {
    unsigned short* wl = (unsigned short*)smc;
    int kbase = blk * 16;
    int tid = threadIdx.x;
    for (int i = tid; i < 2048; i += 256) {
        int kl = i >> 7, n = i & 127;
        float v = (n < 64) ? a.U[(size_t)(kbase + kl) * 64 + n]
                           : a.V[(size_t)(kbase + kl) * 64 + (n - 64)];
        wl[kl * 128 + n] = bf16ru(v);
    }
    __syncthreads();
    {
        int i = tid;
        int kg = i >> 7, n = i & 127;
        int k0 = kbase + kg * 8;
        ushort4 o0, o1;
        o0.x = wl[(kg * 8 + 0) * 128 + n]; o0.y = wl[(kg * 8 + 1) * 128 + n];
        o0.z = wl[(kg * 8 + 2) * 128 + n]; o0.w = wl[(kg * 8 + 3) * 128 + n];
        o1.x = wl[(kg * 8 + 4) * 128 + n]; o1.y = wl[(kg * 8 + 5) * 128 + n];
        o1.z = wl[(kg * 8 + 6) * 128 + n]; o1.w = wl[(kg * 8 + 7) * 128 + n];
        size_t off = (size_t)(n >> 4) * 4096 + (k0 >> 5) * 512 + ((k0 >> 3) & 3) * 128 + (n & 15) * 8;
        *(ushort4*)&a.uvB[off]     = o0;
        *(ushort4*)&a.uvB[off + 4] = o1;
    }
}

// biasPM: [bp2|bm2] @ [U|V], 8 blocks x 32 outputs x 8 lanes
__device__ void biasPM_f(const P& a, int blk) {
    int tid = threadIdx.x;
    int o = blk * 32 + (tid >> 3), e = tid & 7;
    const float* bb = (o < 128) ? a.bp2 : a.bm2;
    int c = o & 127;
    const float* uv = (c < 64) ? (a.U + c) : (a.V + (c - 64));
    float acc = 0.f;
    for (int d = e * 32; d < e * 32 + 32; ++d)
        acc = fmaf(bb[d], uv[(size_t)d * 64], acc);
    acc += __shfl_xor(acc, 1);
    acc += __shfl_xor(acc, 2);
    acc += __shfl_xor(acc, 4);
    if (e == 0) a.biasPM[o] = acc;
}

// alpha -> per-node {parS (masked->1024), aprod}. 256 blocks
__device__ void alpha_f(const P& a, int blk) {
    int t = threadIdx.x, wv = t >> 6, lane = t & 63;
    int node = blk * 4 + wv;
    int slot = lane >> 3, e = lane & 7;
    int par = a.pid[node * 8 + slot];          // par==0 <=> masked
    const float4* qk = (const float4*)(a.concept_q + (size_t)node * 256);
    const float4* qp = (const float4*)(a.concept_q + (size_t)par * 256);
    float dq = 0, np = 0, ns = 0;
#pragma unroll
    for (int i = 0; i < 8; ++i) {
        float4 x = qp[e * 8 + i], y = qk[e * 8 + i];
        dq += x.x * y.x + x.y * y.y + x.z * y.z + x.w * y.w;
        np += x.x * x.x + x.y * x.y + x.z * x.z + x.w * x.w;
        ns += y.x * y.x + y.y * y.y + y.z * y.z + y.w * y.w;
    }
#pragma unroll
    for (int mk = 1; mk <= 4; mk <<= 1) {
        dq += __shfl_xor(dq, mk); np += __shfl_xor(np, mk); ns += __shfl_xor(ns, mk);
    }
    float score = dq / fmaxf(sqrtf(np) * sqrtf(ns), 1e-24f);
    float sc[8]; int pv[8];
#pragma unroll
    for (int s = 0; s < 8; ++s) { sc[s] = __shfl(score, s * 8); pv[s] = __shfl(par, s * 8); }
    float mx = -1e30f;
#pragma unroll
    for (int s = 0; s < 8; ++s) if (pv[s] != 0) mx = fmaxf(mx, sc[s]);
    float sum = 0.f;
#pragma unroll
    for (int s = 0; s < 8; ++s) sum += (pv[s] != 0) ? expf(sc[s] - mx) : 0.0f;
    float ap = 1.0f;
#pragma unroll
    for (int s = 0; s < 8; ++s) if (pv[s] != 0) ap *= expf(sc[s] - mx) / sum;
    if (lane == 0) a.aprod[node] = ap;
    if (e == 0) a.parS[node * 8 + slot] = (par != 0) ? (unsigned short)par : (unsigned short)1024;
}

// ===== levels: EXACT descending wave-synchronous sweep (parents strictly higher-index) =====
// chunk c = nodes [c*64, c*64+64), processed c=15..0 by wave 0; in-chunk deps fix up
// via ballot-terminated loop (P(parent in same chunk) small -> ~2-3 iters).
__device__ void levels_f(const P& a, int* smemI) {
    volatile int* lvl = smemI;                          // 1024 ints
    unsigned short* parL = (unsigned short*)(smemI + 1024);   // 8192 ushort
    int* cnt  = smemI + 1024 + 4096;                    // 1024
    int* ofs  = smemI + 1024 + 4096 + 1024;             // 1024
    int* ping = smemI + 1024 + 4096 + 2048;             // 256
    int* pong = ping + 256;                             // 256
    int* mflag = pong + 256;                            // 2
    int t = threadIdx.x;
    for (int i = t; i < 8192; i += 256) parL[i] = (unsigned short)a.pid[i];
    for (int i = t; i < 1024; i += 256) lvl[i] = 0;
    if (t == 0) mflag[1] = 0;
    __syncthreads();
    if (t < 64) {
        for (int c = 15; c >= 0; --c) {
            int n = c * 64 + t;
            ushort4 pA = *(const ushort4*)&parL[n * 8];
            ushort4 pB = *(const ushort4*)&parL[n * 8 + 4];
            for (;;) {
                int mx = -1;
                if (pA.x) mx = max(mx, lvl[pA.x]);
                if (pA.y) mx = max(mx, lvl[pA.y]);
                if (pA.z) mx = max(mx, lvl[pA.z]);
                if (pA.w) mx = max(mx, lvl[pA.w]);
                if (pB.x) mx = max(mx, lvl[pB.x]);
                if (pB.y) mx = max(mx, lvl[pB.y]);
                if (pB.z) mx = max(mx, lvl[pB.z]);
                if (pB.w) mx = max(mx, lvl[pB.w]);
                int nl = mx + 1;                      // no parents -> 0
                bool ch = (nl > lvl[n]);
                if (ch) lvl[n] = nl;
                if (__ballot(ch) == 0ULL) break;
            }
        }
    }
    __syncthreads();
    // max level + counting sort by level (256 threads, 4 nodes each)
    int lm = 0;
    for (int r = 0; r < 4; ++r) lm = max(lm, lvl[t * 4 + r]);
    atomicMax(&mflag[1], lm);
    for (int r = 0; r < 4; ++r) cnt[t * 4 + r] = 0;
    __syncthreads();
    for (int r = 0; r < 4; ++r) atomicAdd(&cnt[lvl[t * 4 + r]], 1);
    __syncthreads();
    int c0 = cnt[t * 4], c1 = cnt[t * 4 + 1], c2 = cnt[t * 4 + 2], c3 = cnt[t * 4 + 3];
    ping[t] = c0 + c1 + c2 + c3;
    __syncthreads();
    int* src = ping; int* dst = pong;
    for (int off = 1; off < 256; off <<= 1) {
        int v = src[t];
        if (t >= off) v += src[t - off];
        dst[t] = v;
        __syncthreads();
        int* tmp = src; src = dst; dst = tmp;
    }
    int excl = (t == 0) ? 0 : src[t - 1];
    ofs[t * 4] = excl; ofs[t * 4 + 1] = excl + c0;
    ofs[t * 4 + 2] = excl + c0 + c1; ofs[t * 4 + 3] = excl + c0 + c1 + c2;
#pragma unroll
    for (int r = 0; r < 4; ++r) a.lvlStart[t * 4 + r] = ofs[t * 4 + r];
    if (t == 0) { a.lvlStart[1024] = 1024; a.nlev[0] = mflag[1] + 1; }
    __syncthreads();
    for (int r = 0; r < 4; ++r) {
        int n = t * 4 + r;
        int pos = atomicAdd(&ofs[lvl[n]], 1);
        a.sorted[pos] = n;
    }
}

__global__ void __launch_bounds__(256) prep0_kernel(P a) {
    __shared__ int smem[7712];   // 30.8 KB: levels needs lvl+parL+sort arrays; others alias
    int bid = blockIdx.x;
    if (bid == 0) { levels_f(a, smem); return; }
    bid -= 1;
    if (bid < 96) {   // W1 split convert
        int mat = bid & 1, rb = bid >> 1;
        int r0 = rb * 16;
        const float* W1 = mat ? a.Wm1 : a.Wp1;
        if (r0 < 512) bconv_f(W1 + (size_t)r0 * 512, mat ? a.w1upM : a.w1upP, 512, 8192, r0, (char*)smem);
        else          bconv_f(W1 + (size_t)r0 * 512, mat ? a.w1lowM : a.w1lowP, 512, 4096, r0 - 512, (char*)smem);
        return;
    }
    bid -= 96;
    if (bid < 96) {   // Wt/Wv
        int sel = bid & 1, ch = bid >> 1;
        bconv_f((sel ? a.Wt : a.Wv) + (size_t)ch * 16 * 256, a.wtvB + sel * 196608, 256, 12288, ch * 16, (char*)smem);
        return;
    }
    bid -= 96;
    if (bid < 24) { bconv_f(a.Wc + (size_t)bid * 16 * 256, a.wcB, 256, 6144, bid * 16, (char*)smem); return; }
    bid -= 24;
    if (bid < 24) { bconv_f(a.Wg1 + (size_t)bid * 16 * 64, a.wg1B, 64, 6144, bid * 16, (char*)smem); return; }
    bid -= 24;
    if (bid < 4) { bconv_f(a.Wg2 + (size_t)bid * 16 * 64, a.wg2B, 64, 1024, bid * 16, (char*)smem); return; }
    bid -= 4;
    if (bid < 64) {
        int mat = bid & 1, ch = bid >> 1;
        aconv_f(mat ? a.Wm2 : a.Wp2, a.w2bf + mat * 131072, ch * 16, 256, 4096);
        return;
    }
    bid -= 64;
    if (bid < 16) { uvconv_f(a, bid, (char*)smem); return; }
    bid -= 16;
    if (bid < 32) { tcv_f(a, bid); return; }
    bid -= 32;
    if (bid < 64) { aconv_f(a.sbert, a.sbbf, bid * 16, 384, 6144); return; }
    bid -= 64;
    if (bid < 256) { alpha_f(a, bid); return; }
    bid -= 256;
    if (bid < 8) { biasPM_f(a, bid); return; }
    bid -= 8;
    { int k = bid * 256 + threadIdx.x; a.tau[k] = 1.0f / (1.0f + expf(-a.tau_logits[k])); }
}

// ================= MFMA 64x64 GEMM helper =================
__device__ __forceinline__ void gemm64(const unsigned short* A, const unsigned short* B,
                                       int K16A, int K16B, int nsteps,
                                       float4v acc[4], int m, int quad) {
    const unsigned short* Ab = A + quad * 128 + m * 8;
    const unsigned short* Bb = B + quad * 128 + m * 8;
    for (int s = 0; s < nsteps; ++s) {
        short8 af = *(const short8*)(Ab + s * 512);
#pragma unroll
        for (int nt = 0; nt < 4; ++nt) {
            short8 bf = *(const short8*)(Bb + (size_t)nt * K16B + s * 512);
            acc[nt] = __builtin_amdgcn_mfma_f32_16x16x32_bf16(af, bf, acc[nt], 0, 0, 0);
        }
    }
}

// ================= prep1: first-stage GEMMs =================
__global__ void __launch_bounds__(256) prep1_kernel(P a) {
    int bid = blockIdx.x;
    int tid = threadIdx.x;
    int wv = tid >> 6, lane = tid & 63;
    int m = lane & 15, quad = lane >> 4;
    float4v acc[4];
#pragma unroll
    for (int i = 0; i < 4; ++i) acc[i] = (float4v)0.0f;

    if (bid < 16) {
        int sel = bid & 1, mt = (bid >> 1) & 1, ntile = bid >> 2;
        const unsigned short* A = a.tvbf + sel * 98304 + (size_t)(mt * 4 + wv) * 12288;
        const unsigned short* B = a.wtvB + sel * 196608 + (size_t)(ntile * 4) * 12288;
        gemm64(A, B, 12288, 12288, 24, acc, m, quad);
        const float* bias = sel ? a.bt : a.bv;
#pragma unroll
        for (int nt = 0; nt < 4; ++nt) {
            int col = ntile * 64 + nt * 16 + m;
            int vtcol = sel * 256 + col;
            float bb = bias[col];
#pragma unroll
            for (int r = 0; r < 4; ++r) {
                int row = mt * 64 + wv * 16 + quad * 4 + r;
                float val = acc[nt][r] * a.sBuf[sel * 128 + row] + bb;
                size_t off = (size_t)(row >> 4) * 8192 + (vtcol >> 5) * 512
                           + ((vtcol >> 3) & 3) * 128 + (row & 15) * 8 + (vtcol & 7);
                a.vtbf[off] = bf16ru(val);
            }
        }
        return;
    }
    bid -= 16;
    if (bid < 64) {
        int mt = bid & 15, ntile = bid >> 4;
        const unsigned short* A = a.sbbf + (size_t)(mt * 4 + wv) * 6144;
        const unsigned short* B = a.wcB + (size_t)(ntile * 4) * 6144;
        gemm64(A, B, 6144, 6144, 12, acc, m, quad);
#pragma unroll
        for (int nt = 0; nt < 4; ++nt) {
            int col = ntile * 64 + nt * 16 + m;
            float bb = a.bc[col];
#pragma unroll
            for (int r = 0; r < 4; ++r) {
                int row = mt * 64 + wv * 16 + quad * 4 + r;
                size_t off = (size_t)(row >> 4) * 4096 + (col >> 5) * 512
                           + ((col >> 3) & 3) * 128 + (row & 15) * 8 + (col & 7);
                a.dbf[off] = bf16ru(acc[nt][r] + bb);
            }
        }
        return;
    }
    bid -= 64;
    if (bid < 16) {
        int mt = bid;
        const unsigned short* A = a.sbbf + (size_t)(mt * 4 + wv) * 6144;
        gemm64(A, a.wg1B, 6144, 6144, 12, acc, m, quad);
#pragma unroll
        for (int nt = 0; nt < 4; ++nt) {
            int col = nt * 16 + m;
            float bb = a.bg1[col];
#pragma unroll
            for (int r = 0; r < 4; ++r) {
                int row = mt * 64 + wv * 16 + quad * 4 + r;
                float x = acc[nt][r] + bb;
                float g = 0.5f * x * (1.0f + erff(x * 0.7071067811865475f));
                size_t off = (size_t)(row >> 4) * 1024 + (col >> 5) * 512
                           + ((col >> 3) & 3) * 128 + (row & 15) * 8 + (col & 7);
                a.ghbf[off] = bf16ru(g);
            }
        }
        return;
    }
    bid -= 16;
    {
        int mat = bid & 1, mt = (bid >> 1) & 7, ntile = bid >> 4;
        const unsigned short* A = a.w2bf + mat * 131072 + (size_t)(mt * 4 + wv) * 4096;
        const unsigned short* B = a.uvB + (size_t)(ntile * 4) * 4096;
        gemm64(A, B, 4096, 4096, 8, acc, m, quad);
        unsigned short* outP = mat ? a.Wmk : a.Wpk;
#pragma unroll
        for (int nt = 0; nt < 4; ++nt) {
            int c = ntile * 64 + nt * 16 + m;
#pragma unroll
            for (int r = 0; r < 4; ++r) {
                int j = mt * 64 + wv * 16 + quad * 4 + r;
                size_t o = (size_t)(j >> 5) * 4096 + (c >> 4) * 512 + ((j >> 3) & 3) * 128
                         + (c & 15) * 8 + (j & 7);
                outP[o] = bf16ru(acc[nt][r]);
            }
        }
    }
}

// ================= prep2: second-stage GEMMs =================
__global__ void __launch_bounds__(256) prep2_kernel(P a) {
    int bid = blockIdx.x;
    int tid = threadIdx.x;
    int wv = tid >> 6, lane = tid & 63;
    int m = lane & 15, quad = lane >> 4;
    if (bid < 256) {
        int mat = bid & 1, mt = (bid >> 1) & 15, ntile = bid >> 5;
        const unsigned short* A = a.dbf + (size_t)(mt * 4 + wv) * 4096 + quad * 128 + m * 8;
        const unsigned short* B = (mat ? a.w1lowM : a.w1lowP) + (size_t)quad * 128 + m * 8;
        unsigned short* Ct = mat ? a.Ctm : a.Ctp;
        float4v acc[4];
#pragma unroll
        for (int i = 0; i < 4; ++i) acc[i] = (float4v)0.0f;
        for (int s = 0; s < 8; ++s) {
            short8 af = *(const short8*)(A + s * 512);
#pragma unroll
            for (int nt = 0; nt < 4; ++nt) {
                short8 bf = *(const short8*)(B + (size_t)(ntile * 4 + nt) * 4096 + s * 512);
                acc[nt] = __builtin_amdgcn_mfma_f32_16x16x32_bf16(af, bf, acc[nt], 0, 0, 0);
            }
        }
        int rowg = mt * 4 + wv;
        int rl = quad * 4;
#pragma unroll
        for (int nt = 0; nt < 4; ++nt) {
            int j = ntile * 64 + nt * 16 + m;
            size_t base = (size_t)rowg * 8192 + (j >> 5) * 512 + ((j >> 3) & 3) * 128 + (j & 7);
#pragma unroll
            for (int rr = 0; rr < 4; ++rr)
                Ct[base + (rl + rr) * 8] = bf16ru(acc[nt][rr]);
        }
        return;
    }
    bid -= 256;
    if (bid < 32) {
        int mat = bid & 1, mt = (bid >> 1) & 1, ntile = bid >> 2;
        const unsigned short* A = a.vtbf + (size_t)(mt * 4 + wv) * 8192 + quad * 128 + m * 8;
        const unsigned short* B = (mat ? a.w1upM : a.w1upP) + (size_t)quad * 128 + m * 8;
        const float* bias = mat ? a.bm1 : a.bp1;
        float* out = mat ? a.Am : a.Ap;
        float4v acc[4];
#pragma unroll
        for (int i = 0; i < 4; ++i) acc[i] = (float4v)0.0f;
        for (int s = 0; s < 16; ++s) {
            short8 af = *(const short8*)(A + s * 512);
#pragma unroll
            for (int nt = 0; nt < 4; ++nt) {
                short8 bf = *(const short8*)(B + (size_t)(ntile * 4 + nt) * 8192 + s * 512);
                acc[nt] = __builtin_amdgcn_mfma_f32_16x16x32_bf16(af, bf, acc[nt], 0, 0, 0);
            }
        }
        int b0r = mt * 64 + wv * 16 + quad * 4;
#pragma unroll
        for (int nt = 0; nt < 4; ++nt) {
            int j = ntile * 64 + nt * 16 + m;
            float bb = bias[j];
#pragma unroll
            for (int rr = 0; rr < 4; ++rr)
                out[(size_t)(b0r + rr) * 512 + j] = acc[nt][rr] + bb;
        }
        return;
    }
    bid -= 32;
    {
        int mt = bid;
        const unsigned short* A = a.ghbf + (size_t)(mt * 4 + wv) * 1024 + quad * 128 + m * 8;
        const unsigned short* B = a.wg2B + (size_t)quad * 128 + m * 8;
        float4v acc[4];
#pragma unroll
        for (int i = 0; i < 4; ++i) acc[i] = (float4v)0.0f;
        for (int s = 0; s < 2; ++s) {
            short8 af = *(const short8*)(A + s * 512);
#pragma unroll
            for (int nt = 0; nt < 4; ++nt) {
                short8 bf = *(const short8*)(B + (size_t)nt * 1024 + s * 512);
                acc[nt] = __builtin_amdgcn_mfma_f32_16x16x32_bf16(af, bf, acc[nt], 0, 0, 0);
            }
        }
#pragma unroll
        for (int nt = 0; nt < 4; ++nt) {
            int col = nt * 16 + m;
            float bb = a.bg2[col];
#pragma unroll
            for (int r = 0; r < 4; ++r) {
                int k = mt * 64 + wv * 16 + quad * 4 + r;
                a.gw[(size_t)k * 64 + col] = (acc[nt][r] + bb) * a.w_out[(size_t)k * 64 + col];
            }
        }
    }
}

// ========== main: LDS-staged (global_load_lds) dbuf W, 4 batches, P/M wave-split ==========
__global__ void __launch_bounds__(512, 2) main_kernel(P a) {
    __shared__ float apL[4096];
    __shared__ char wbuf[2][16384];
    int tid = threadIdx.x;
    int wv2 = tid >> 6, lane = tid & 63;
    int mat = wv2 >> 2, sub = wv2 & 3;
    int m = lane & 15, quad = lane >> 4;
    int b0 = (blockIdx.x >> 4) * 4;
    int k0 = (blockIdx.x & 15) << 6;

    for (int i = tid; i < 1024; i += 512) {
        int arr = i >> 7, off = i & 127;
        const float* src = ((arr >> 2) ? a.Am : a.Ap) + (size_t)(b0 + (arr & 3)) * 512;
        ((float4*)apL)[i] = ((const float4*)src)[off];
    }

    const char* wg = ((wv2 < 4) ? (const char*)a.Wpk : (const char*)a.Wmk)
                   + (wv2 & 3) * 2048 + lane * 16;
    char* wl0 = &wbuf[0][wv2 * 2048];
    char* wl1 = &wbuf[1][wv2 * 2048];

    const unsigned short* Ct = mat ? a.Ctm : a.Ctp;
    const float* aL = apL + mat * 2048;
    int kt = (k0 >> 4) + sub;
    const char* ctB = (const char*)Ct + (size_t)kt * 16384 + quad * 256 + m * 16;

    float4v acc[4][8];
#pragma unroll
    for (int b = 0; b < 4; ++b)
#pragma unroll
        for (int i = 0; i < 8; ++i) acc[b][i] = (float4v)0.0f;

    glds16(wg, wl0);
    glds16(wg + 1024, wl0 + 1024);
    uint4 crN = *(const uint4*)(ctB);
    __syncthreads();

    for (int n = 0; n < 16; ++n) {
        if (n < 15) {
            char* dst = ((n + 1) & 1) ? wl1 : wl0;
            glds16(wg + (n + 1) * 8192, dst);
            glds16(wg + (n + 1) * 8192 + 1024, dst + 1024);
        }
        uint4 cr = crN;
        if (n < 15) crN = *(const uint4*)(ctB + (n + 1) * 1024);
        union { uint4 u; short8 s; } fa[4];
        const float* aj = aL + n * 32 + quad * 8;
#pragma unroll
        for (int b = 0; b < 4; ++b) {
            float4v x0 = *(const float4v*)(aj + b * 512);
            float4v x1 = *(const float4v*)(aj + b * 512 + 4);
            float2v v;
            v.x = x0[0]; v.y = x0[1]; fa[b].u.x = packpair(v, cr.x);
            v.x = x0[2]; v.y = x0[3]; fa[b].u.y = packpair(v, cr.y);
            v.x = x1[0]; v.y = x1[1]; fa[b].u.z = packpair(v, cr.z);
            v.x = x1[2]; v.y = x1[3]; fa[b].u.w = packpair(v, cr.w);
        }
        const char* wB = &wbuf[n & 1][0] + mat * 8192 + quad * 256 + m * 16;
#pragma unroll
        for (int nt = 0; nt < 8; ++nt) {
            short8 wf = *(const short8*)(wB + nt * 1024);
            acc[0][nt] = __builtin_amdgcn_mfma_f32_16x16x32_bf16(fa[0].s, wf, acc[0][nt], 0, 0, 0);
            acc[1][nt] = __builtin_amdgcn_mfma_f32_16x16x32_bf16(fa[1].s, wf, acc[1][nt], 0, 0, 0);
            acc[2][nt] = __builtin_amdgcn_mfma_f32_16x16x32_bf16(fa[2].s, wf, acc[2][nt], 0, 0, 0);
            acc[3][nt] = __builtin_amdgcn_mfma_f32_16x16x32_bf16(fa[3].s, wf, acc[3][nt], 0, 0, 0);
        }
        __syncthreads();
    }

    float* xbuf = (float*)wbuf;
    int kk[4]; float tv[4];
#pragma unroll
    for (int r = 0; r < 4; ++r) { kk[r] = k0 + sub * 16 + quad * 4 + r; tv[r] = a.tau[kk[r]]; }
    float lsum[4][4] = {};
#pragma unroll
    for (int t4 = 0; t4 < 4; ++t4) {
        __syncthreads();
        if (mat == 1) {
#pragma unroll
            for (int b = 0; b < 4; ++b) {
                int slot = (sub * 4 + b) * 64 + lane;
#pragma unroll
                for (int r = 0; r < 4; ++r) {
                    xbuf[r * 1024 + slot]       = acc[b][t4][r];
                    xbuf[(r + 4) * 1024 + slot] = acc[b][t4 + 4][r];
                }
            }
        }
        __syncthreads();
        if (mat == 0) {
            int cU = t4 * 16 + m, cV = cU + 64;
            float bPu = a.biasPM[cU], bMu = a.biasPM[128 + cU];
            float bPv = a.biasPM[cV], bMv = a.biasPM[128 + cV];
#pragma unroll
            for (int b = 0; b < 4; ++b) {
                int slot = (sub * 4 + b) * 64 + lane;
#pragma unroll
                for (int r = 0; r < 4; ++r) {
                    float g = a.gw[(size_t)kk[r] * 64 + cU];
                    float u  = tv[r] * (acc[b][t4][r] + bPu)
                             + (1.0f - tv[r]) * (xbuf[r * 1024 + slot] + bMu);
                    float vx = tv[r] * (acc[b][t4 + 4][r] + bPv)
                             + (1.0f - tv[r]) * (xbuf[(r + 4) * 1024 + slot] + bMv);
                    lsum[b][r] = fmaf(u * vx, g, lsum[b][r]);
                }
            }
        }
    }
    if (mat == 0) {
#pragma unroll
        for (int r = 0; r < 4; ++r) {
            float bo = a.b_out[kk[r]];
#pragma unroll
            for (int b = 0; b < 4; ++b) {
                float s = lsum[b][r];
                s += __shfl_xor(s, 1); s += __shfl_xor(s, 2); s += __shfl_xor(s, 4); s += __shfl_xor(s, 8);
                if (m == 0)
                    a.pOut[(size_t)(b0 + b) * 1024 + kk[r]] = 1.0f / (1.0f + expf(-(s + bo)));
            }
        }
    }
}

// ========== scan: one wave per batch, graph state in LDS, no level barriers ==========
#define PH_STRIDE 1056
__global__ void __launch_bounds__(256) scan_kernel(P a) {
    __shared__ float ph[4 * PH_STRIDE];
    __shared__ float aprodL[1024];
    __shared__ unsigned short parL[8192];
    __shared__ short sortedL[1024];
    __shared__ int lvlStartL[1025];
    int t = threadIdx.x;
    int b0 = blockIdx.x * 4;
    for (int i = t; i < 1024; i += 256) ((uint4*)parL)[i] = ((const uint4*)a.parS)[i];
    for (int i = t; i < 1024; i += 256) {
        aprodL[i] = a.aprod[i];
        sortedL[i] = (short)a.sorted[i];
        lvlStartL[i] = a.lvlStart[i];
    }
    if (t == 0) lvlStartL[1024] = 1024;
    for (int i = t; i < 4096; i += 256) {
        int bb = i >> 10, k = i & 1023;
        ph[bb * PH_STRIDE + k] = a.pOut[(size_t)(b0 + bb) * 1024 + k];
    }
    if (t < 4) ph[t * PH_STRIDE + 1024] = 1.0f;
    __syncthreads();
    int nlev = a.nlev[0];
    int w = t >> 6, lane = t & 63;
    float* myph = ph + w * PH_STRIDE;
    for (int L = 1; L < nlev; ++L) {
        int s0 = lvlStartL[L], s1 = lvlStartL[L + 1];
        for (int i = s0 + lane; i < s1; i += 64) {
            int node = sortedL[i];
            ushort4 pA = *(const ushort4*)&parL[node * 8];
            ushort4 pB = *(const ushort4*)&parL[node * 8 + 4];
            float prod = aprodL[node];
            prod *= myph[pA.x] * myph[pA.y];
            prod *= myph[pA.z] * myph[pA.w];
            prod *= myph[pB.x] * myph[pB.y];
            prod *= myph[pB.z] * myph[pB.w];
            myph[node] = fmaf(0.35f, myph[node], 0.65f * prod);
        }
    }
    __syncthreads();
    for (int i = t; i < 4096; i += 256) {
        int bb = i >> 10, k = i & 1023;
        a.pOut[(size_t)(b0 + bb) * 1024 + k] = ph[bb * PH_STRIDE + k];
    }
}

extern "C" void kernel_launch(void* const* d_in, const int* in_sizes, int n_in,
                              void* d_out, int out_size, void* d_ws, size_t ws_size,
                              hipStream_t stream) {
    P a;
    a.t_clip = (const float*)d_in[0];
    a.v_clip = (const float*)d_in[1];
    a.sbert  = (const float*)d_in[2];
    a.Wt  = (const float*)d_in[3];  a.bt  = (const float*)d_in[4];
    a.Wv  = (const float*)d_in[5];  a.bv  = (const float*)d_in[6];
    a.Wc  = (const float*)d_in[7];  a.bc  = (const float*)d_in[8];
    a.Wp1 = (const float*)d_in[9];  a.bp1 = (const float*)d_in[10];
    a.Wp2 = (const float*)d_in[11]; a.bp2 = (const float*)d_in[12];
    a.Wm1 = (const float*)d_in[13]; a.bm1 = (const float*)d_in[14];
    a.Wm2 = (const float*)d_in[15]; a.bm2 = (const float*)d_in[16];
    a.tau_logits = (const float*)d_in[17];
    a.U   = (const float*)d_in[18]; a.V   = (const float*)d_in[19];
    a.Wg1 = (const float*)d_in[20]; a.bg1 = (const float*)d_in[21];
    a.Wg2 = (const float*)d_in[22]; a.bg2 = (const float*)d_in[23];
    a.w_out = (const float*)d_in[24]; a.b_out = (const float*)d_in[25];
    a.concept_q = (const float*)d_in[26];
    a.pid = (const int*)d_in[27];
    // d_in[28] parents_mask unused (par==0 <=> masked); d_in[29] order unused

    char* w = (char*)d_ws;
    a.Ctp  = (unsigned short*)(w + 0);
    a.Ctm  = (unsigned short*)(w + 1048576);
    a.tvbf = (unsigned short*)(w + 0);
    a.sbbf = (unsigned short*)(w + 393216);
    a.wtvB = (unsigned short*)(w + 1179648);
    a.wcB  = (unsigned short*)(w + 1966080);
    a.w1upP  = (unsigned short*)(w + 2162688);
    a.w1upM  = (unsigned short*)(w + 2686976);
    a.w1lowP = (unsigned short*)(w + 3211264);
    a.w1lowM = (unsigned short*)(w + 3473408);
    a.wg1B   = (unsigned short*)(w + 3735552);
    a.wg2B   = (unsigned short*)(w + 3784704);
    a.w2bf   = (unsigned short*)(w + 3792896);
    a.uvB    = (unsigned short*)(w + 4317184);
    a.vtbf   = (unsigned short*)(w + 4382720);
    a.dbf    = (unsigned short*)(w + 4513792);
    a.ghbf   = (unsigned short*)(w + 5038080);
    a.Wpk    = (unsigned short*)(w + 5169152);
    a.Wmk    = (unsigned short*)(w + 5300224);
    a.Ap     = (float*)(w + 5431296);
    a.Am     = (float*)(w + 5693440);
    a.biasPM = (float*)(w + 5955584);
    a.tau    = (float*)(w + 5956608);
    a.gw     = (float*)(w + 5960704);
    a.sBuf   = (float*)(w + 6222848);
    a.parS   = (unsigned short*)(w + 6223872);
    a.aprod  = (float*)(w + 6240256);
    a.sorted = (int*)(w + 6244352);
    a.lvlStart = (int*)(w + 6248448);
    a.nlev     = (int*)(w + 6252672);
    a.pOut = (float*)d_out;

    prep0_kernel<<<689, 256, 0, stream>>>(a);
    prep1_kernel<<<128, 256, 0, stream>>>(a);
    prep2_kernel<<<304, 256, 0, stream>>>(a);
    main_kernel<<<512, 512, 0, stream>>>(a);
    scan_kernel<<<32, 256, 0, stream>>>(a);
}